// Round 1
// baseline (199.663 us; speedup 1.0000x reference)
//
#include <hip/hip_runtime.h>
#include <math.h>

#define BB 8
#define CC 64
#define HH 32
#define WW 32
#define HW 1024
#define NEGN 256
#define TEMP 2.0f
#define FACTOR 0.8f
#define EPSF 1e-8f

// ---------------------------------------------------------------------------
// Kernel 0: transpose views_2 (B, C, HW) -> z2t (B, HW, C) so the per-(p,n)
// gather in the main kernel reads 64 contiguous floats (16x float4).
// ---------------------------------------------------------------------------
__global__ __launch_bounds__(256) void transpose_z2(
    const float* __restrict__ z2, float* __restrict__ z2t) {
    int idx = blockIdx.x * 256 + threadIdx.x;   // over B*HW*C, c fastest
    int c = idx & (CC - 1);
    int q = (idx >> 6) & (HW - 1);
    int b = idx >> 16;                          // 6 + 10 bits
    z2t[idx] = z2[((size_t)(b * CC + c)) * HW + q];
}

// ---------------------------------------------------------------------------
// Kernel 1: one block per (b, p); thread t handles negative n = t.
//   - stage z1[:, p] (64 floats) + center rgb into LDS
//   - per-n: euc/rgb squared dists (block-reduced -> weight[p]),
//            dot + |pn|^2 over C via contiguous float4 gather from z2t
//   - sim_neg = min(|cos| * weight, 1)  -> atomicAdd into accSim[b*NEG+n]
//   - thread 0: sim0 contribution       -> atomicAdd into accSim0[b]
// ---------------------------------------------------------------------------
__global__ __launch_bounds__(256) void contrastive_main(
    const float* __restrict__ z1,    // (B, C, HW)
    const float* __restrict__ z2t,   // (B, HW, C)
    const float* __restrict__ img,   // (3, HW)
    const int*   __restrict__ nidx,  // (B, 2, HW, NEG)
    float* __restrict__ accSim,      // (B, NEG)
    float* __restrict__ accSim0)     // (B)
{
    const int p = blockIdx.x & (HW - 1);
    const int b = blockIdx.x >> 10;
    const int t = threadIdx.x;       // n index

    __shared__ float z1s[CC];
    __shared__ float cen[3];
    __shared__ float redE[4], redR[4];
    __shared__ float sh_weight, sh_z1sq;

    if (t < CC)
        z1s[t] = z1[((size_t)(b * CC + t)) * HW + p];
    if (t >= CC && t < CC + 3)
        cen[t - CC] = img[(t - CC) * HW + p];
    __syncthreads();

    // z1sq via wave 0 shuffle reduction
    if (t < 64) {
        float v = z1s[t];
        float zq = v * v;
        #pragma unroll
        for (int off = 32; off; off >>= 1) zq += __shfl_down(zq, off);
        if (t == 0) sh_z1sq = zq;
    }

    // ---- per-n gather of indices + spatial/rgb squared distances ----
    const int r  = nidx[(((size_t)(b * 2 + 0)) * HW + p) * NEGN + t];
    const int cc = nidx[(((size_t)(b * 2 + 1)) * HW + p) * NEGN + t];
    const int q  = r * WW + cc;

    const float hp = (float)(p >> 5);   // p // W
    const float wp = (float)(p & 31);   // p %  W
    const float dh = hp - (float)r;
    const float dw = wp - (float)cc;
    float deuc = dh * dh + dw * dw;

    const float d0 = cen[0] - img[0 * HW + q];
    const float d1 = cen[1] - img[1 * HW + q];
    const float d2 = cen[2] - img[2 * HW + q];
    float drgb = d0 * d0 + d1 * d1 + d2 * d2;

    // ---- dot + |pn|^2 over C (contiguous float4 from z2t row) ----
    const float4* __restrict__ row4 =
        reinterpret_cast<const float4*>(z2t + ((size_t)(b * HW + q)) * CC);
    const float4* z1s4 = reinterpret_cast<const float4*>(z1s);
    float dot = 0.f, pnsq = 0.f;
    #pragma unroll
    for (int i = 0; i < CC / 4; ++i) {
        const float4 v = row4[i];
        const float4 a = z1s4[i];
        dot  += v.x * a.x + v.y * a.y + v.z * a.z + v.w * a.w;
        pnsq += v.x * v.x + v.y * v.y + v.z * v.z + v.w * v.w;
    }

    // ---- block-reduce deuc / drgb (4 waves) ----
    float se = deuc, sr = drgb;
    #pragma unroll
    for (int off = 32; off; off >>= 1) {
        se += __shfl_down(se, off);
        sr += __shfl_down(sr, off);
    }
    const int wid = t >> 6;
    if ((t & 63) == 0) { redE[wid] = se; redR[wid] = sr; }
    __syncthreads();

    if (t == 0) {
        const float sumE = redE[0] + redE[1] + redE[2] + redE[3];
        const float sumR = redR[0] + redR[1] + redR[2] + redR[3];
        const float euc_norm = sqrtf((float)((HH - 1) * (HH - 1) + (WW - 1) * (WW - 1)));
        const float euc = sqrtf(sumE) / euc_norm;
        const float rgb = sqrtf(sumR) / sqrtf(3.0f);
        sh_weight = euc * FACTOR + rgb * (1.0f - FACTOR);

        // sim0 contribution for this pixel
        const float z1sq = sh_z1sq;
        const float cos0 = z1sq / fmaxf(z1sq, EPSF);
        const float sim0 = fminf(fabsf(cos0), 1.0f);
        atomicAdd(accSim0 + b, sim0);
    }
    __syncthreads();

    const float weight = sh_weight;
    const float z1n = sqrtf(sh_z1sq);
    const float cosv = dot / fmaxf(z1n * sqrtf(pnsq), EPSF);
    const float sim_neg = fminf(fabsf(cosv * weight), 1.0f);

    atomicAdd(accSim + b * NEGN + t, sim_neg);
}

// ---------------------------------------------------------------------------
// Kernel 2: finalize. loss is linear in sum(log1p terms) + sum(logp), so one
// block of 256 threads (thread n, loop over b) suffices.
// ---------------------------------------------------------------------------
__global__ __launch_bounds__(256) void finalize(
    const float* __restrict__ accSim,
    const float* __restrict__ accSim0,
    float* __restrict__ out)
{
    const int t = threadIdx.x;
    float ssum = 0.f, lsum = 0.f;
    #pragma unroll
    for (int b = 0; b < BB; ++b) {
        const float s = accSim[b * NEGN + t] * (1.0f / HW) * (1.0f / TEMP);
        ssum += s;
        lsum += fmaxf(log1pf(-s), -100.0f);
    }
    __shared__ float rs[4], rl[4];
    #pragma unroll
    for (int off = 32; off; off >>= 1) {
        ssum += __shfl_down(ssum, off);
        lsum += __shfl_down(lsum, off);
    }
    if ((t & 63) == 0) { rs[t >> 6] = ssum; rl[t >> 6] = lsum; }
    __syncthreads();

    if (t == 0) {
        const float S = rs[0] + rs[1] + rs[2] + rs[3];
        const float L = rl[0] + rl[1] + rl[2] + rl[3];
        float logpsum = 0.f, sim0sum = 0.f;
        #pragma unroll
        for (int b = 0; b < BB; ++b) {
            const float s0 = accSim0[b] * (1.0f / HW);
            sim0sum += s0;
            logpsum += fmaxf(logf(s0), -100.0f);
        }
        out[0] = -(logpsum + L) / ((float)(NEGN + 1) * (float)BB);
        out[1] = sim0sum / (float)BB;
        out[2] = S / (float)NEGN * TEMP / (float)BB;
    }
}

extern "C" void kernel_launch(void* const* d_in, const int* in_sizes, int n_in,
                              void* d_out, int out_size, void* d_ws, size_t ws_size,
                              hipStream_t stream) {
    const float* v1   = (const float*)d_in[0];   // views_1 (B,C,H,W) f32
    const float* v2   = (const float*)d_in[1];   // views_2 (B,C,H,W) f32
    const float* img  = (const float*)d_in[2];   // img (1,3,H,W) f32
    const int*   nidx = (const int*)  d_in[3];   // neg_idx (B,2,HW,NEG) i32

    float* ws      = (float*)d_ws;
    float* z2t     = ws;                          // B*HW*C floats (2 MB)
    float* accSim  = ws + (size_t)BB * HW * CC;   // B*NEG
    float* accSim0 = accSim + BB * NEGN;          // B

    hipMemsetAsync(accSim, 0, (BB * NEGN + BB) * sizeof(float), stream);

    transpose_z2<<<(BB * HW * CC) / 256, 256, 0, stream>>>(v2, z2t);
    contrastive_main<<<BB * HW, 256, 0, stream>>>(v1, z2t, img, nidx, accSim, accSim0);
    finalize<<<1, 256, 0, stream>>>(accSim, accSim0, (float*)d_out);
}

// Round 2
// 106.208 us; speedup vs baseline: 1.8799x; 1.8799x over previous
//
#include <hip/hip_runtime.h>
#include <math.h>

#define BB 8
#define CC 64
#define HH 32
#define WW 32
#define HW 1024
#define NEGN 256
#define TEMP 2.0f
#define FACTOR 0.8f
#define EPSF 1e-8f
#define PT 8            // p-rows per block

// ---------------------------------------------------------------------------
// Fused kernel: one block per (b, p-tile of 8 rows).
// Phase A: dense GEMM D[pp][q] = sum_c z1[b,c,p0+pp] * z2[b,c,q] for all q,
//          coalesced float4 streaming of z2[b] (L2-resident), accumulators in
//          registers, result + per-q norms written to LDS.
// Phase B: per-(p,n) gather is now a 4B LDS read from Dt; img staged in LDS;
//          weight via half-wave shuffle reduction; per-block partial sums ->
//          one atomicAdd per n per block.
// LDS: 2 + 32 + 4 + 12 + 8 + ~0 = ~58 KB  (< 64 KB per-WG cap)
// ---------------------------------------------------------------------------
__global__ __launch_bounds__(256) void contrastive_fused(
    const float* __restrict__ z1,    // (B, C, HW)
    const float* __restrict__ z2,    // (B, C, HW)
    const float* __restrict__ img,   // (3, HW)
    const int*   __restrict__ nidx,  // (B, 2, HW, NEG)
    float* __restrict__ accSim,      // (B, NEG)
    float* __restrict__ accSim0)     // (B)
{
    __shared__ float As_s[CC * PT];       // [k][pp]   2 KB
    __shared__ float Dt_s[PT * HW];       // [pp][q]  32 KB
    __shared__ float normq_s[HW];         //           4 KB
    __shared__ float imgs[3 * HW];        //          12 KB
    __shared__ float simpart[PT * NEGN];  // [pp][n]   8 KB
    __shared__ float z1sqs[PT];

    const int t  = threadIdx.x;
    const int b  = blockIdx.x >> 7;
    const int p0 = (blockIdx.x & 127) * PT;

    const int lane32 = t & 31;   // n-group lane
    const int pp_b   = t >> 5;   // which p this thread handles in phase B
    const int p_b    = p0 + pp_b;

    // ---- prefetch nidx early (strided-n mapping: n = lane32 + 32*j) ----
    int rr[8], cc_[8];
    const size_t nbase = ((size_t)(b * 2) * HW + p_b) * NEGN;
    #pragma unroll
    for (int j = 0; j < 8; ++j) {
        rr[j]  = nidx[nbase + lane32 + 32 * j];
        cc_[j] = nidx[nbase + (size_t)HW * NEGN + lane32 + 32 * j];
    }

    // ---- stage z1 panel + img into LDS ----
    for (int i = t; i < CC * PT; i += 256) {
        const int c = i >> 3, pp = i & 7;
        As_s[i] = z1[((size_t)(b * CC + c)) * HW + p0 + pp];
    }
    for (int i = t; i < 3 * HW; i += 256) imgs[i] = img[i];
    __syncthreads();

    if (t < PT) {
        float s = 0.f;
        #pragma unroll
        for (int c = 0; c < CC; ++c) { const float v = As_s[c * PT + t]; s += v * v; }
        z1sqs[t] = s;
    }

    // ---- phase A: GEMM, thread t owns q = 4t..4t+3 for all 8 p ----
    const float4* __restrict__ z2f4 =
        reinterpret_cast<const float4*>(z2 + (size_t)b * CC * HW);
    float4 acc[PT];
    #pragma unroll
    for (int pp = 0; pp < PT; ++pp) acc[pp] = make_float4(0.f, 0.f, 0.f, 0.f);
    float4 sq = make_float4(0.f, 0.f, 0.f, 0.f);

    #pragma unroll 8
    for (int k = 0; k < CC; ++k) {
        const float4 bv = z2f4[k * (HW / 4) + t];
        sq.x = fmaf(bv.x, bv.x, sq.x);
        sq.y = fmaf(bv.y, bv.y, sq.y);
        sq.z = fmaf(bv.z, bv.z, sq.z);
        sq.w = fmaf(bv.w, bv.w, sq.w);
        const float4 a03 = reinterpret_cast<const float4*>(As_s)[k * 2];
        const float4 a47 = reinterpret_cast<const float4*>(As_s)[k * 2 + 1];
        const float av[8] = {a03.x, a03.y, a03.z, a03.w, a47.x, a47.y, a47.z, a47.w};
        #pragma unroll
        for (int pp = 0; pp < PT; ++pp) {
            acc[pp].x = fmaf(av[pp], bv.x, acc[pp].x);
            acc[pp].y = fmaf(av[pp], bv.y, acc[pp].y);
            acc[pp].z = fmaf(av[pp], bv.z, acc[pp].z);
            acc[pp].w = fmaf(av[pp], bv.w, acc[pp].w);
        }
    }
    float4* Dt4 = reinterpret_cast<float4*>(Dt_s);
    #pragma unroll
    for (int pp = 0; pp < PT; ++pp) Dt4[pp * (HW / 4) + t] = acc[pp];
    reinterpret_cast<float4*>(normq_s)[t] =
        make_float4(sqrtf(sq.x), sqrtf(sq.y), sqrtf(sq.z), sqrtf(sq.w));
    __syncthreads();

    // ---- phase B: gather + weight + sim, all from LDS ----
    const float z1sq = z1sqs[pp_b];
    const float z1n  = sqrtf(z1sq);
    const float cen0 = imgs[p_b], cen1 = imgs[HW + p_b], cen2 = imgs[2 * HW + p_b];
    const float hp = (float)(p_b >> 5), wp = (float)(p_b & 31);

    float se = 0.f, sr = 0.f;
    float cosv[8];
    #pragma unroll
    for (int j = 0; j < 8; ++j) {
        const int q = rr[j] * WW + cc_[j];
        const float dh = hp - (float)rr[j], dw = wp - (float)cc_[j];
        se += dh * dh + dw * dw;
        const float d0 = cen0 - imgs[q];
        const float d1 = cen1 - imgs[HW + q];
        const float d2 = cen2 - imgs[2 * HW + q];
        sr += d0 * d0 + d1 * d1 + d2 * d2;
        const float dot = Dt_s[pp_b * HW + q];
        const float pnn = normq_s[q];
        cosv[j] = dot / fmaxf(z1n * pnn, EPSF);
    }
    // reduce over the 32 lanes sharing this p (xor<=16 stays within half-wave)
    #pragma unroll
    for (int off = 16; off; off >>= 1) {
        se += __shfl_xor(se, off);
        sr += __shfl_xor(sr, off);
    }
    const float euc_norm = sqrtf((float)((HH - 1) * (HH - 1) + (WW - 1) * (WW - 1)));
    const float weight = sqrtf(se) / euc_norm * FACTOR +
                         sqrtf(sr) / sqrtf(3.0f) * (1.0f - FACTOR);
    #pragma unroll
    for (int j = 0; j < 8; ++j)
        simpart[pp_b * NEGN + lane32 + 32 * j] = fminf(fabsf(cosv[j] * weight), 1.0f);
    __syncthreads();

    // per-n sum over the 8 p's in this block -> one atomic per n
    float s = 0.f;
    #pragma unroll
    for (int pp = 0; pp < PT; ++pp) s += simpart[pp * NEGN + t];
    atomicAdd(accSim + b * NEGN + t, s);

    // sim0 contributions (8 p's) -> one atomic per block
    if (t < PT) {
        const float c0 = z1sq / fmaxf(z1sq, EPSF);
        float s0 = fminf(fabsf(c0), 1.0f);
        #pragma unroll
        for (int off = 4; off; off >>= 1) s0 += __shfl_xor(s0, off);
        if (t == 0) atomicAdd(accSim0 + b, s0);
    }
}

// ---------------------------------------------------------------------------
// Finalize: loss is linear in the per-(b,n) sums; one block suffices.
// ---------------------------------------------------------------------------
__global__ __launch_bounds__(256) void finalize(
    const float* __restrict__ accSim,
    const float* __restrict__ accSim0,
    float* __restrict__ out)
{
    const int t = threadIdx.x;
    float ssum = 0.f, lsum = 0.f;
    #pragma unroll
    for (int b = 0; b < BB; ++b) {
        const float s = accSim[b * NEGN + t] * (1.0f / HW) * (1.0f / TEMP);
        ssum += s;
        lsum += fmaxf(log1pf(-s), -100.0f);
    }
    __shared__ float rs[4], rl[4];
    #pragma unroll
    for (int off = 32; off; off >>= 1) {
        ssum += __shfl_down(ssum, off);
        lsum += __shfl_down(lsum, off);
    }
    if ((t & 63) == 0) { rs[t >> 6] = ssum; rl[t >> 6] = lsum; }
    __syncthreads();

    if (t == 0) {
        const float S = rs[0] + rs[1] + rs[2] + rs[3];
        const float L = rl[0] + rl[1] + rl[2] + rl[3];
        float logpsum = 0.f, sim0sum = 0.f;
        #pragma unroll
        for (int b = 0; b < BB; ++b) {
            const float s0 = accSim0[b] * (1.0f / HW);
            sim0sum += s0;
            logpsum += fmaxf(logf(s0), -100.0f);
        }
        out[0] = -(logpsum + L) / ((float)(NEGN + 1) * (float)BB);
        out[1] = sim0sum / (float)BB;
        out[2] = S / (float)NEGN * TEMP / (float)BB;
    }
}

extern "C" void kernel_launch(void* const* d_in, const int* in_sizes, int n_in,
                              void* d_out, int out_size, void* d_ws, size_t ws_size,
                              hipStream_t stream) {
    const float* v1   = (const float*)d_in[0];
    const float* v2   = (const float*)d_in[1];
    const float* img  = (const float*)d_in[2];
    const int*   nidx = (const int*)  d_in[3];

    float* accSim  = (float*)d_ws;            // B*NEG
    float* accSim0 = accSim + BB * NEGN;      // B

    hipMemsetAsync(accSim, 0, (BB * NEGN + BB) * sizeof(float), stream);

    contrastive_fused<<<BB * (HW / PT), 256, 0, stream>>>(
        v1, v2, img, nidx, accSim, accSim0);
    finalize<<<1, 256, 0, stream>>>(accSim, accSim0, (float*)d_out);
}